// Round 6
// baseline (227.354 us; speedup 1.0000x reference)
//
#include <hip/hip_runtime.h>
#include <hip/hip_bf16.h>

// Problem constants
#define B_  16
#define N_  512
#define M_  16
#define H_  8
#define D_  128
#define BN_ 8192   // B_*N_
#define NB  8      // nodes per block in main kernel

typedef __attribute__((ext_vector_type(4))) float          f32x4;
typedef __attribute__((ext_vector_type(2))) _Float16       f16x2;
typedef __attribute__((ext_vector_type(4))) _Float16       f16x4;
typedef __attribute__((ext_vector_type(8))) unsigned short u16x8;
typedef __attribute__((ext_vector_type(8))) _Float16       f16x8;

static __device__ __forceinline__ float bf2f(__hip_bfloat16 x) { return __bfloat162float(x); }
static __device__ __forceinline__ unsigned short f2bu(float x) {
    __hip_bfloat16 b = __float2bfloat16(x);
    return *reinterpret_cast<unsigned short*>(&b);
}
static __device__ __forceinline__ float bu2f(unsigned short u) {
    return __uint_as_float(((unsigned int)u) << 16);
}

// Load/store policy: interpret float tensors as f32 or bf16.
template <bool F32>
struct Pol {
    static __device__ __forceinline__ float ld(const void* p, int i) {
        if constexpr (F32) return ((const float*)p)[i];
        else               return bf2f(((const __hip_bfloat16*)p)[i]);
    }
    static __device__ __forceinline__ float2 ld2(const void* p, long i) {  // i%2==0
        if constexpr (F32) return *(const float2*)((const float*)p + i);
        else {
            const ushort2 u = *(const ushort2*)((const unsigned short*)p + i);
            return make_float2(bu2f(u.x), bu2f(u.y));
        }
    }
    static __device__ __forceinline__ float4 ld4(const void* p, int i) {  // i%4==0
        if constexpr (F32) return *(const float4*)((const float*)p + i);
        else {
            const ushort4 u = *(const ushort4*)((const unsigned short*)p + i);
            return make_float4(bu2f(u.x), bu2f(u.y), bu2f(u.z), bu2f(u.w));
        }
    }
    static __device__ __forceinline__ void ld8(const void* p, long i, float* v) {  // i%8==0
        if constexpr (F32) {
            const float4 a = *(const float4*)((const float*)p + i);
            const float4 b = *(const float4*)((const float*)p + i + 4);
            v[0]=a.x; v[1]=a.y; v[2]=a.z; v[3]=a.w;
            v[4]=b.x; v[5]=b.y; v[6]=b.z; v[7]=b.w;
        } else {
            const u16x8 u = *(const u16x8*)((const unsigned short*)p + i);
            #pragma unroll
            for (int j = 0; j < 8; ++j) v[j] = bu2f(u[j]);
        }
    }
    static __device__ __forceinline__ void st8(void* p, long i, const float* v) {  // i%8==0
        if constexpr (F32) {
            *(float4*)((float*)p + i)     = make_float4(v[0], v[1], v[2], v[3]);
            *(float4*)((float*)p + i + 4) = make_float4(v[4], v[5], v[6], v[7]);
        } else {
            u16x8 u;
            #pragma unroll
            for (int j = 0; j < 8; ++j) u[j] = f2bu(v[j]);
            *(u16x8*)((unsigned short*)p + i) = u;
        }
    }
};

// Dtype probe (verbatim): f32 buffers read as bf16 at even index give
// random-exponent garbage; genuine bf16 stays small.
static __device__ __forceinline__ bool probe_is_f32(const void* h) {
    bool is_f32 = false;
    const __hip_bfloat16* hb = (const __hip_bfloat16*)h;
    for (int i = 0; i < 128; ++i) {
        const float v = bf2f(hb[2 * i]);
        if (!(fabsf(v) < 1e4f)) is_f32 = true;
    }
    return is_f32;
}

// ---------------------------------------------------------------------------
// kA (prep + scores, grid 1024, 256 thr):
//   blk <  512 : WeffT[o][hd] = f16( sum_e W[hd][e] * Wo[(h*128+e)][o] )
//                [byte-identical math to proven k0 blk<512]
//   blk >= 512 : score block for 16 nodes.  Computes its own wsrc/wdst into
//                LDS (removes the k0->k1 dependency so both halves fuse into
//                one launch), then the proven k1 dot.
// ---------------------------------------------------------------------------
template <bool F32>
static __device__ __forceinline__ void kA_body(
        const void* __restrict__ W,  const void* __restrict__ Wo,
        const void* __restrict__ a_src, const void* __restrict__ a_dst,
        const void* __restrict__ h,
        _Float16* __restrict__ WeffT,
        _Float16* __restrict__ ssrc_h, _Float16* __restrict__ sdst_h,
        float* sbuf /* shared, 2*16*132 floats */) {
    using P = Pol<F32>;
    const int blk = blockIdx.x;
    const int t   = threadIdx.x;
    if (blk < 512) {
        // ---- Weff (proven) ----
        float* wrow = sbuf;
        const int half = t >> 7, o = t & 127;
        const int hd = blk * 2 + half;               // hd = h*128 + d
        wrow[half * 128 + o] = P::ld(W, hd * 128 + o);
        __syncthreads();
        const int hh = hd >> 7;
        float acc = 0.f;
        #pragma unroll 8
        for (int e = 0; e < 128; ++e)
            acc += wrow[half * 128 + e] * P::ld(Wo, (hh * 128 + e) * 128 + o);
        WeffT[(size_t)o * 1024 + hd] = (_Float16)acc;
    } else {
        // ---- scores for 16 nodes ----
        float* hls = sbuf;               // [16][132]
        float* wls = sbuf + 16 * 132;    // [16][132]  row c = which*8+head
        const int bn0 = (blk - 512) * 16;
        // stage h rows
        {
            const int r = t >> 4, c0 = (t & 15) * 8;
            float v[8];
            P::ld8(h, (long)(bn0 + r) * 128 + c0, v);
            #pragma unroll
            for (int j = 0; j < 8; ++j) hls[r * 132 + c0 + j] = v[j];
        }
        // compute wls: wsrc/wdst[h][d] = sum_e W[h][d][e] * a_{src,dst}[h][e]
        {
            const int h_  = t >> 5;              // head 0..7
            const int d00 = (t & 31) * 4;        // 4 d's per thread
            #pragma unroll
            for (int dd = 0; dd < 4; ++dd) {
                const int d = d00 + dd;
                float accS = 0.f, accD = 0.f;
                for (int e0 = 0; e0 < 128; e0 += 8) {
                    float wv[8], as[8], ad[8];
                    P::ld8(W, (long)(h_ * 128 + d) * 128 + e0, wv);
                    P::ld8(a_src, h_ * 128 + e0, as);
                    P::ld8(a_dst, h_ * 128 + e0, ad);
                    #pragma unroll
                    for (int j = 0; j < 8; ++j) {
                        accS += wv[j] * as[j];
                        accD += wv[j] * ad[j];
                    }
                }
                wls[h_ * 132 + d]       = accS;   // which=0 (src) row h_
                wls[(8 + h_) * 132 + d] = accD;   // which=1 (dst) row 8+h_
            }
        }
        __syncthreads();
        // proven k1 dot
        const int n = t >> 4, c = t & 15;
        float acc = 0.f;
        #pragma unroll
        for (int e = 0; e < 128; e += 4) {
            const float4 hv = *(const float4*)(hls + n * 132 + e);
            const float4 wv = *(const float4*)(wls + c * 132 + e);
            acc += hv.x * wv.x + hv.y * wv.y + hv.z * wv.z + hv.w * wv.w;
        }
        const int node = bn0 + n;
        if (c < 8) ssrc_h[node * 8 + c]       = (_Float16)acc;
        else       sdst_h[node * 8 + (c - 8)] = (_Float16)acc;
    }
}

__global__ __launch_bounds__(256) void kA(
        const void* W, const void* Wo, const void* a_src, const void* a_dst,
        const void* h, _Float16* WeffT, _Float16* ssrc_h, _Float16* sdst_h) {
    __shared__ float sbuf[2 * 16 * 132];
    if (probe_is_f32(h)) kA_body<true >(W, Wo, a_src, a_dst, h, WeffT, ssrc_h, sdst_h, sbuf);
    else                 kA_body<false>(W, Wo, a_src, a_dst, h, WeffT, ssrc_h, sdst_h, sbuf);
}

// ---------------------------------------------------------------------------
// Main fused kernel. 8 nodes/block, 512 threads (8 waves), grid 1024
// -> 4 blocks/CU co-resident = 32 waves/CU (100% occupancy).
// All GEMMs on the PROVEN v_mfma_f32_16x16x16_f16 layout:
//   A lane(lo,hi) reg j = A[lo][4*hi+j]; B = B[4*hi+j][lo]; D reg q -> row
//   4*hi+q, col lo.  With NB=8, A rows 8-15 duplicate rows 0-7 (lo&7);
//   D rows 8-15 are discarded (only lanes hi<2 store).
// Zh f16 in LDS, XOR swizzle byte^=((row&7)<<4).  LDS ~= 25.9 KB.
// ---------------------------------------------------------------------------
struct __align__(16) Smem {
    union {
        _Float16 Zh[NB][1024];                 // 16384   P4 -> G1 (f16, swizzled)
        struct {
            float    ts[NB][132];              // 4224    LN1 -> FF1/FF2 (padded)
            _Float16 us[NB][260];              // 4160    FF1 -> FF2 (padded)
            float    ys[NB][128];              // 4096    FF2 -> LN2
        } ff;
    } u;
    float hs[NB][128];                         // 4096    residual
    union {
        float attn[NB][16][8];                 // 4096    P2 -> P4
        float yln[NB][128];                    // 4096    G1 -> LN1
    } v;
    int   nls[NB][16];                         // 512
    int   adjs[NB][16];                        // 512
    float ssrc[NB][8];                         // 256
};

template <bool F32>
static __device__ __forceinline__ void gat_body(
        Smem& s,
        const void* __restrict__ h,
        const int*  __restrict__ adj,
        const int*  __restrict__ n_list,
        const _Float16* __restrict__ ssrc_h,
        const _Float16* __restrict__ sdst_h,
        const _Float16* __restrict__ WeffT,
        const void* __restrict__ g1, const void* __restrict__ bb1,
        const void* __restrict__ w1, const void* __restrict__ fb1,
        const void* __restrict__ w2, const void* __restrict__ fb2,
        const void* __restrict__ g2, const void* __restrict__ bb2,
        void* __restrict__ out) {
    using P = Pol<F32>;
    const int t   = threadIdx.x;
    const int bn0 = blockIdx.x * NB;
    const int b   = bn0 >> 9;                  // 512 nodes per batch
    const int l   = t & 63;
    const int w   = t >> 6;                    // wave 0..7
    const int lo  = l & 15;
    const int hi  = l >> 4;

    // ---- P1: self rows (all 512) + neighbor lists + gathered ssrc (parallel jobs)
    {
        const int r = t >> 6, c0 = (t & 63) * 2;
        const float2 v = P::ld2(h, (long)(bn0 + r) * 128 + c0);
        *(float2*)&s.hs[r][c0] = v;
    }
    if (t < 128) {
        const int r = t >> 4, m = t & 15;
        s.nls[r][m]  = n_list[(bn0 + r) * M_ + m] & (N_ - 1);
        s.adjs[r][m] = adj[(bn0 + r) * M_ + m];
    } else if (t < 128 + NB * 8) {
        const int i = t - 128;
        s.ssrc[i >> 3][i & 7] = (float)ssrc_h[bn0 * 8 + i];
    }
    __syncthreads();

    // ---- P2: scores = mask(leaky(s_src + s_dst[nl]))   (128 threads)
    if (t < NB * 16) {
        const int r = t >> 4, m = t & 15;
        const int nbr = s.nls[r][m];
        const f16x8 sd = *(const f16x8*)(sdst_h + (size_t)(b * N_ + nbr) * 8);
        const int amask = s.adjs[r][m];
        float sc[8];
        #pragma unroll
        for (int hh = 0; hh < 8; ++hh) {
            float x = s.ssrc[r][hh] + (float)sd[hh];
            x = x > 0.f ? x : 0.2f * x;        // leaky_relu BEFORE mask (ref order)
            if (amask == 0) x = -1e9f;
            sc[hh] = x;
        }
        *(float4*)&s.v.attn[r][m][0] = make_float4(sc[0], sc[1], sc[2], sc[3]);
        *(float4*)&s.v.attn[r][m][4] = make_float4(sc[4], sc[5], sc[6], sc[7]);
    }
    __syncthreads();

    // ---- P3: softmax over m   (64 threads)
    if (t < NB * 8) {
        const int r = t >> 3, hh = t & 7;
        float mx = -3.4e38f;
        #pragma unroll
        for (int m = 0; m < 16; ++m) mx = fmaxf(mx, s.v.attn[r][m][hh]);
        float ex[16], sum = 0.f;
        #pragma unroll
        for (int m = 0; m < 16; ++m) { ex[m] = __expf(s.v.attn[r][m][hh] - mx); sum += ex[m]; }
        const float inv = 1.f / sum;
        #pragma unroll
        for (int m = 0; m < 16; ++m) s.v.attn[r][m][hh] = ex[m] * inv;
    }
    __syncthreads();

    // ---- P4: Z[r][hh][d] = sum_m attn[r][m][hh] * h[nl[r][m]][d]
    //      512 threads: 64 threads/node, 2 d each.  (f16, swizzled)
    {
        const int r = t >> 6, dc = t & 63, d0 = dc * 2;
        float z[8][2];
        #pragma unroll
        for (int hh = 0; hh < 8; ++hh) { z[hh][0] = 0.f; z[hh][1] = 0.f; }
        #pragma unroll 4
        for (int m = 0; m < 16; ++m) {
            const int nbr = s.nls[r][m];
            const float2 hv = P::ld2(h, (long)(b * N_ + nbr) * 128 + d0);
            const float4 a0 = *(const float4*)&s.v.attn[r][m][0];
            const float4 a1 = *(const float4*)&s.v.attn[r][m][4];
            const float av[8] = { a0.x, a0.y, a0.z, a0.w, a1.x, a1.y, a1.z, a1.w };
            #pragma unroll
            for (int hh = 0; hh < 8; ++hh) {
                z[hh][0] += av[hh] * hv.x;
                z[hh][1] += av[hh] * hv.y;
            }
        }
        char* zb = (char*)&s.u.Zh[0][0] + r * 2048;
        const int xo = (r & 7) << 4;
        #pragma unroll
        for (int hh = 0; hh < 8; ++hh) {
            f16x2 vv;
            vv[0] = (_Float16)z[hh][0];
            vv[1] = (_Float16)z[hh][1];
            *(f16x2*)(zb + ((hh * 256 + dc * 4) ^ xo)) = vv;
        }
    }
    __syncthreads();

    // ---- G1: yln = Zh @ WeffT^T + hs   (MFMA 16x16x16, K=1024; 8 waves x 16 cols)
    {
        const char* za  = (const char*)&s.u.Zh[0][0] + (lo & 7) * 2048;
        const int   xo  = (lo & 7) << 4;
        const char* wb0 = (const char*)(WeffT + (size_t)(w * 16 + lo) * 1024);
        f32x4 acc0 = {0.f, 0.f, 0.f, 0.f};
        #pragma unroll 8
        for (int ks = 0; ks < 64; ++ks) {
            const int kb = ks * 32 + hi * 8;           // byte offset of k = ks*16 + hi*4
            const f16x4 a  = *(const f16x4*)(za + (kb ^ xo));
            const f16x4 b0 = *(const f16x4*)(wb0 + kb);
            acc0 = __builtin_amdgcn_mfma_f32_16x16x16f16(a, b0, acc0, 0, 0, 0);
        }
        if (hi < 2) {
            const int o0 = w * 16 + lo;
            #pragma unroll
            for (int q = 0; q < 4; ++q) {
                const int rr = hi * 4 + q;
                s.v.yln[rr][o0] = acc0[q] + s.hs[rr][o0];
            }
        }
    }
    __syncthreads();

    // ---- LN1 -> ts (f32, padded rows). 16 threads per row (128 threads).
    if (t < NB * 16) {
        const int r = t >> 4, j0 = (t & 15) * 8;
        const float4 x0 = *(const float4*)&s.v.yln[r][j0];
        const float4 x1 = *(const float4*)&s.v.yln[r][j0 + 4];
        const float x[8] = { x0.x, x0.y, x0.z, x0.w, x1.x, x1.y, x1.z, x1.w };
        float sm = 0.f, ss = 0.f;
        #pragma unroll
        for (int j = 0; j < 8; ++j) { sm += x[j]; ss += x[j] * x[j]; }
        #pragma unroll
        for (int off = 8; off > 0; off >>= 1) {
            sm += __shfl_xor(sm, off);
            ss += __shfl_xor(ss, off);
        }
        const float mu   = sm * (1.f / 128.f);
        const float var  = ss * (1.f / 128.f) - mu * mu;
        const float rstd = rsqrtf(var + 1e-5f);
        float gv[8], bv[8];
        P::ld8(g1, j0, gv);
        P::ld8(bb1, j0, bv);
        #pragma unroll
        for (int j = 0; j < 8; ++j)
            s.u.ff.ts[r][j0 + j] = (x[j] - mu) * rstd * gv[j] + bv[j];
    }
    __syncthreads();

    // ---- FF1: us = relu(ts @ w1 + b1)  (MFMA; 8 waves x 32 cols; K=128)
    {
        f32x4 acc[2] = { {0.f,0.f,0.f,0.f}, {0.f,0.f,0.f,0.f} };
        #pragma unroll
        for (int ks = 0; ks < 8; ++ks) {
            const int k = ks * 16 + hi * 4;
            const float4 tv = *(const float4*)&s.u.ff.ts[lo & 7][k];
            f16x4 a;
            a[0] = (_Float16)tv.x; a[1] = (_Float16)tv.y;
            a[2] = (_Float16)tv.z; a[3] = (_Float16)tv.w;
            #pragma unroll
            for (int nt = 0; nt < 2; ++nt) {
                const int o = w * 32 + nt * 16 + lo;
                f16x4 bb;
                #pragma unroll
                for (int j = 0; j < 4; ++j) bb[j] = (_Float16)P::ld(w1, (k + j) * 256 + o);
                acc[nt] = __builtin_amdgcn_mfma_f32_16x16x16f16(a, bb, acc[nt], 0, 0, 0);
            }
        }
        if (hi < 2) {
            #pragma unroll
            for (int nt = 0; nt < 2; ++nt) {
                const int o = w * 32 + nt * 16 + lo;
                const float bias = P::ld(fb1, o);
                #pragma unroll
                for (int q = 0; q < 4; ++q)
                    s.u.ff.us[hi * 4 + q][o] = (_Float16)fmaxf(acc[nt][q] + bias, 0.f);
            }
        }
    }
    __syncthreads();

    // ---- FF2: ys = us @ w2 + b2 + ts  (MFMA; 8 waves x 16 cols; K=256)
    {
        const int o0 = w * 16 + lo;
        f32x4 acc = {0.f, 0.f, 0.f, 0.f};
        #pragma unroll
        for (int ks = 0; ks < 16; ++ks) {
            const int k = ks * 16 + hi * 4;
            const f16x4 a = *(const f16x4*)&s.u.ff.us[lo & 7][k];
            f16x4 bb;
            #pragma unroll
            for (int j = 0; j < 4; ++j) bb[j] = (_Float16)P::ld(w2, (k + j) * 128 + o0);
            acc = __builtin_amdgcn_mfma_f32_16x16x16f16(a, bb, acc, 0, 0, 0);
        }
        if (hi < 2) {
            const float bias = P::ld(fb2, o0);
            #pragma unroll
            for (int q = 0; q < 4; ++q) {
                const int rr = hi * 4 + q;
                s.u.ff.ys[rr][o0] = acc[q] + bias + s.u.ff.ts[rr][o0];
            }
        }
    }
    __syncthreads();

    // ---- LN2 -> out. 16 threads per row (128 threads).
    if (t < NB * 16) {
        const int r = t >> 4, j0 = (t & 15) * 8;
        const float4 x0 = *(const float4*)&s.u.ff.ys[r][j0];
        const float4 x1 = *(const float4*)&s.u.ff.ys[r][j0 + 4];
        const float x[8] = { x0.x, x0.y, x0.z, x0.w, x1.x, x1.y, x1.z, x1.w };
        float sm = 0.f, ss = 0.f;
        #pragma unroll
        for (int j = 0; j < 8; ++j) { sm += x[j]; ss += x[j] * x[j]; }
        #pragma unroll
        for (int off = 8; off > 0; off >>= 1) {
            sm += __shfl_xor(sm, off);
            ss += __shfl_xor(ss, off);
        }
        const float mu   = sm * (1.f / 128.f);
        const float var  = ss * (1.f / 128.f) - mu * mu;
        const float rstd = rsqrtf(var + 1e-5f);
        float gv[8], bv[8], o8[8];
        P::ld8(g2, j0, gv);
        P::ld8(bb2, j0, bv);
        #pragma unroll
        for (int j = 0; j < 8; ++j) o8[j] = (x[j] - mu) * rstd * gv[j] + bv[j];
        P::st8(out, (long)(bn0 + r) * 128 + j0, o8);
    }
}

__global__ __launch_bounds__(512) void k_gat(
        const void* __restrict__ h,
        const int*  __restrict__ adj,
        const int*  __restrict__ n_list,
        const _Float16* __restrict__ ssrc_h,
        const _Float16* __restrict__ sdst_h,
        const _Float16* __restrict__ WeffT,
        const void* __restrict__ g1, const void* __restrict__ bb1,
        const void* __restrict__ w1, const void* __restrict__ fb1,
        const void* __restrict__ w2, const void* __restrict__ fb2,
        const void* __restrict__ g2, const void* __restrict__ bb2,
        void* __restrict__ out) {
    __shared__ Smem s;
    if (probe_is_f32(h))
        gat_body<true >(s, h, adj, n_list, ssrc_h, sdst_h, WeffT,
                        g1, bb1, w1, fb1, w2, fb2, g2, bb2, out);
    else
        gat_body<false>(s, h, adj, n_list, ssrc_h, sdst_h, WeffT,
                        g1, bb1, w1, fb1, w2, fb2, g2, bb2, out);
}

// ---------------------------------------------------------------------------
extern "C" void kernel_launch(void* const* d_in, const int* in_sizes, int n_in,
                              void* d_out, int out_size, void* d_ws, size_t ws_size,
                              hipStream_t stream) {
    (void)in_sizes; (void)n_in; (void)out_size; (void)ws_size;

    // ws layout (bytes) — total 532480, identical footprint to the proven kernel:
    //   [unused] [     0,   8192)  (was wsrc/wdst — now computed per-block)
    //   ssrc     [  8192, 139264)  f16[8192*8]
    //   sdst     [139264, 270336)  f16[8192*8]
    //   WeffT    [270336, 532480)  f16[128][1024]
    char* wsb = (char*)d_ws;
    _Float16*  ssrc  = (_Float16*)(wsb + 8192);
    _Float16*  sdst  = (_Float16*)(wsb + 139264);
    _Float16*  WeffT = (_Float16*)(wsb + 270336);

    kA<<<1024, 256, 0, stream>>>(d_in[3], d_in[6], d_in[4], d_in[5], d_in[0],
                                 WeffT, ssrc, sdst);
    k_gat<<<BN_ / NB, 512, 0, stream>>>(
        d_in[0], (const int*)d_in[1], (const int*)d_in[2], ssrc, sdst, WeffT,
        d_in[7], d_in[8], d_in[9], d_in[10], d_in[11], d_in[12],
        d_in[13], d_in[14], d_out);
}

// Round 7
// 161.126 us; speedup vs baseline: 1.4110x; 1.4110x over previous
//
#include <hip/hip_runtime.h>
#include <hip/hip_bf16.h>

// Problem constants
#define B_  16
#define N_  512
#define M_  16
#define H_  8
#define D_  128
#define BN_ 8192   // B_*N_
#define NB  16     // nodes per block in main kernel

typedef __attribute__((ext_vector_type(4))) float          f32x4;
typedef __attribute__((ext_vector_type(2))) _Float16       f16x2;
typedef __attribute__((ext_vector_type(4))) _Float16       f16x4;
typedef __attribute__((ext_vector_type(8))) unsigned short u16x8;
typedef __attribute__((ext_vector_type(8))) _Float16       f16x8;

static __device__ __forceinline__ float bf2f(__hip_bfloat16 x) { return __bfloat162float(x); }
static __device__ __forceinline__ unsigned short f2bu(float x) {
    __hip_bfloat16 b = __float2bfloat16(x);
    return *reinterpret_cast<unsigned short*>(&b);
}
static __device__ __forceinline__ float bu2f(unsigned short u) {
    return __uint_as_float(((unsigned int)u) << 16);
}

// Load/store policy: interpret float tensors as f32 or bf16.
template <bool F32>
struct Pol {
    static __device__ __forceinline__ float ld(const void* p, int i) {
        if constexpr (F32) return ((const float*)p)[i];
        else               return bf2f(((const __hip_bfloat16*)p)[i]);
    }
    static __device__ __forceinline__ float2 ld2(const void* p, long i) {  // i%2==0
        if constexpr (F32) return *(const float2*)((const float*)p + i);
        else {
            const ushort2 u = *(const ushort2*)((const unsigned short*)p + i);
            return make_float2(bu2f(u.x), bu2f(u.y));
        }
    }
    static __device__ __forceinline__ float4 ld4(const void* p, int i) {  // i%4==0
        if constexpr (F32) return *(const float4*)((const float*)p + i);
        else {
            const ushort4 u = *(const ushort4*)((const unsigned short*)p + i);
            return make_float4(bu2f(u.x), bu2f(u.y), bu2f(u.z), bu2f(u.w));
        }
    }
    static __device__ __forceinline__ void ld8(const void* p, long i, float* v) {  // i%8==0
        if constexpr (F32) {
            const float4 a = *(const float4*)((const float*)p + i);
            const float4 b = *(const float4*)((const float*)p + i + 4);
            v[0]=a.x; v[1]=a.y; v[2]=a.z; v[3]=a.w;
            v[4]=b.x; v[5]=b.y; v[6]=b.z; v[7]=b.w;
        } else {
            const u16x8 u = *(const u16x8*)((const unsigned short*)p + i);
            #pragma unroll
            for (int j = 0; j < 8; ++j) v[j] = bu2f(u[j]);
        }
    }
    static __device__ __forceinline__ void st8(void* p, long i, const float* v) {  // i%8==0
        if constexpr (F32) {
            *(float4*)((float*)p + i)     = make_float4(v[0], v[1], v[2], v[3]);
            *(float4*)((float*)p + i + 4) = make_float4(v[4], v[5], v[6], v[7]);
        } else {
            u16x8 u;
            #pragma unroll
            for (int j = 0; j < 8; ++j) u[j] = f2bu(v[j]);
            *(u16x8*)((unsigned short*)p + i) = u;
        }
    }
};

// Dtype probe (verbatim): f32 buffers read as bf16 at even index give
// random-exponent garbage; genuine bf16 stays small.
static __device__ __forceinline__ bool probe_is_f32(const void* h) {
    bool is_f32 = false;
    const __hip_bfloat16* hb = (const __hip_bfloat16*)h;
    for (int i = 0; i < 128; ++i) {
        const float v = bf2f(hb[2 * i]);
        if (!(fabsf(v) < 1e4f)) is_f32 = true;
    }
    return is_f32;
}

// ---------------------------------------------------------------------------
// K0 (prep, grid 520):  [byte-identical to passing round 5]
//   blk <  512 : WeffT[o][hd] = f16( sum_e W[hd][e] * Wo[(h*128+e)][o] )
//   blk >= 512 : wsrc/wdst[h][d] = sum_e W[h][d][e] * a_{src,dst}[h][e]  (f32)
// ---------------------------------------------------------------------------
template <bool F32>
static __device__ __forceinline__ void k0_body(
        const void* __restrict__ W,  const void* __restrict__ Wo,
        const void* __restrict__ a_src, const void* __restrict__ a_dst,
        float* __restrict__ wsrc, float* __restrict__ wdst,
        _Float16* __restrict__ WeffT, float* wrow /* shared [2*128] */) {
    using P = Pol<F32>;
    const int blk = blockIdx.x;
    const int t   = threadIdx.x;
    if (blk < 512) {
        const int half = t >> 7, o = t & 127;
        const int hd = blk * 2 + half;               // hd = h*128 + d
        wrow[half * 128 + o] = P::ld(W, hd * 128 + o);
        __syncthreads();
        const int hh = hd >> 7;
        float acc = 0.f;
        #pragma unroll 8
        for (int e = 0; e < 128; ++e)
            acc += wrow[half * 128 + e] * P::ld(Wo, (hh * 128 + e) * 128 + o);
        WeffT[(size_t)o * 1024 + hd] = (_Float16)acc;
    } else {
        const int hh = blk - 512;
        const int which = t >> 7, d = t & 127;
        const void* av = which ? a_dst : a_src;
        const int wbase = hh * (D_ * D_) + d * 128;
        float acc = 0.f;
        #pragma unroll 8
        for (int e = 0; e < 128; e += 4) {
            const float4 wv = P::ld4(W, wbase + e);
            const float4 aa = P::ld4(av, hh * 128 + e);
            acc += wv.x * aa.x + wv.y * aa.y + wv.z * aa.z + wv.w * aa.w;
        }
        (which ? wdst : wsrc)[hh * 128 + d] = acc;
    }
}

__global__ __launch_bounds__(256) void k0(
        const void* W, const void* Wo, const void* a_src, const void* a_dst,
        const void* h, float* wsrc, float* wdst, _Float16* WeffT) {
    __shared__ float wrow[2 * 128];
    if (probe_is_f32(h)) k0_body<true >(W, Wo, a_src, a_dst, wsrc, wdst, WeffT, wrow);
    else                 k0_body<false>(W, Wo, a_src, a_dst, wsrc, wdst, WeffT, wrow);
}

// ---------------------------------------------------------------------------
// K1: scores.  [byte-identical to passing round 5]
// ---------------------------------------------------------------------------
template <bool F32>
static __device__ __forceinline__ void k1_body(
        const void* __restrict__ h, const float* __restrict__ wsrc,
        const float* __restrict__ wdst, _Float16* __restrict__ ssrc_h,
        _Float16* __restrict__ sdst_h, float* hls /*[16*132]*/, float* wls /*[16*132]*/) {
    using P = Pol<F32>;
    const int t   = threadIdx.x;
    const int bn0 = blockIdx.x * 16;
    {
        const int r = t >> 4, c0 = (t & 15) * 8;
        float v[8];
        P::ld8(h, (long)(bn0 + r) * 128 + c0, v);
        #pragma unroll
        for (int j = 0; j < 8; ++j) hls[r * 132 + c0 + j] = v[j];
        const int c = t >> 4;                         // c = which*8 + head
        const float* wp = (c >> 3) ? wdst : wsrc;
        const int woff = (c & 7) * 128 + c0;
        #pragma unroll
        for (int j = 0; j < 8; ++j) wls[c * 132 + c0 + j] = wp[woff + j];
    }
    __syncthreads();
    const int n = t >> 4, c = t & 15;
    float acc = 0.f;
    #pragma unroll
    for (int e = 0; e < 128; e += 4) {
        const float4 hv = *(const float4*)(hls + n * 132 + e);
        const float4 wv = *(const float4*)(wls + c * 132 + e);
        acc += hv.x * wv.x + hv.y * wv.y + hv.z * wv.z + hv.w * wv.w;
    }
    const int node = bn0 + n;
    if (c < 8) ssrc_h[node * 8 + c]       = (_Float16)acc;
    else       sdst_h[node * 8 + (c - 8)] = (_Float16)acc;
}

__global__ __launch_bounds__(256) void k1(const void* h, const float* wsrc,
                                          const float* wdst, _Float16* ssrc_h,
                                          _Float16* sdst_h) {
    __shared__ float hls[16 * 132];
    __shared__ float wls[16 * 132];
    if (probe_is_f32(h)) k1_body<true >(h, wsrc, wdst, ssrc_h, sdst_h, hls, wls);
    else                 k1_body<false>(h, wsrc, wdst, ssrc_h, sdst_h, hls, wls);
}

// ---------------------------------------------------------------------------
// Main fused kernel. 16 nodes/block, 1024 threads (16 waves), grid 512
// -> 2 blocks/CU x 16 waves = 32 waves/CU (100% wave capacity).
// All GEMMs on the PROVEN v_mfma_f32_16x16x16_f16 layout:
//   A lane(lo,hi) reg j = A[lo][4*hi+j]; B = B[4*hi+j][lo]; D reg q -> row
//   4*hi+q, col lo.
//   G1 : 16 waves = 8 col-groups x 2 K-halves (partials reduced via s.part)
//   FF1: 16 waves x 16 cols, full K=128
//   FF2: 8 col-groups x 2 K-halves (partials via s.part)
// Zh f16 in LDS, XOR swizzle byte^=((row&7)<<4).  LDS ~= 59.9 KB.
// ---------------------------------------------------------------------------
struct __align__(16) Smem {
    union {
        _Float16 Zh[NB][1024];                 // 32768   P4 -> G1 (f16, swizzled)
        struct {
            float    ts[NB][132];              // 8448    LN1 -> FF1/FF2 (padded)
            _Float16 us[NB][260];              // 8320    FF1 -> FF2 (padded)
            float    ys[NB][128];              // 8192    FF2 -> LN2
        } ff;
    } u;
    float part[NB][128];                       // 8192    K-split partials
    float hs[NB][128];                         // 8192    residual
    union {
        float attn[NB][16][8];                 // 8192    P2 -> P4
        float yln[NB][128];                    // 8192    G1 -> LN1
    } v;
    int   nls[NB][16];                         // 1024
    int   adjs[NB][16];                        // 1024
    float ssrc[NB][8];                         // 512
};

template <bool F32>
static __device__ __forceinline__ void gat_body(
        Smem& s,
        const void* __restrict__ h,
        const int*  __restrict__ adj,
        const int*  __restrict__ n_list,
        const _Float16* __restrict__ ssrc_h,
        const _Float16* __restrict__ sdst_h,
        const _Float16* __restrict__ WeffT,
        const void* __restrict__ g1, const void* __restrict__ bb1,
        const void* __restrict__ w1, const void* __restrict__ fb1,
        const void* __restrict__ w2, const void* __restrict__ fb2,
        const void* __restrict__ g2, const void* __restrict__ bb2,
        void* __restrict__ out) {
    using P = Pol<F32>;
    const int t   = threadIdx.x;
    const int bn0 = blockIdx.x * NB;
    const int b   = bn0 >> 9;                  // 512 nodes per batch
    const int l   = t & 63;
    const int w   = t >> 6;                    // wave 0..15
    const int lo  = l & 15;
    const int hi  = l >> 4;
    const int wo  = w & 7;                     // col-group for K-split GEMMs
    const int kh  = w >> 3;                    // K-half

    // ---- P1: self rows (all 1024) + neighbor lists + gathered ssrc
    {
        const int r = t >> 6, c0 = (t & 63) * 2;
        const float2 v = P::ld2(h, (long)(bn0 + r) * 128 + c0);
        *(float2*)&s.hs[r][c0] = v;
    }
    if (t < 256) {
        const int r = t >> 4, m = t & 15;
        s.nls[r][m]  = n_list[(bn0 + r) * M_ + m] & (N_ - 1);
        s.adjs[r][m] = adj[(bn0 + r) * M_ + m];
    } else if (t < 256 + NB * 8) {
        const int i = t - 256;
        s.ssrc[i >> 3][i & 7] = (float)ssrc_h[bn0 * 8 + i];
    }
    __syncthreads();

    // ---- P2: scores = mask(leaky(s_src + s_dst[nl]))   (256 threads)
    if (t < NB * 16) {
        const int r = t >> 4, m = t & 15;
        const int nbr = s.nls[r][m];
        const f16x8 sd = *(const f16x8*)(sdst_h + (size_t)(b * N_ + nbr) * 8);
        const int amask = s.adjs[r][m];
        float sc[8];
        #pragma unroll
        for (int hh = 0; hh < 8; ++hh) {
            float x = s.ssrc[r][hh] + (float)sd[hh];
            x = x > 0.f ? x : 0.2f * x;        // leaky_relu BEFORE mask (ref order)
            if (amask == 0) x = -1e9f;
            sc[hh] = x;
        }
        *(float4*)&s.v.attn[r][m][0] = make_float4(sc[0], sc[1], sc[2], sc[3]);
        *(float4*)&s.v.attn[r][m][4] = make_float4(sc[4], sc[5], sc[6], sc[7]);
    }
    __syncthreads();

    // ---- P3: softmax over m   (128 threads)
    if (t < NB * 8) {
        const int r = t >> 3, hh = t & 7;
        float mx = -3.4e38f;
        #pragma unroll
        for (int m = 0; m < 16; ++m) mx = fmaxf(mx, s.v.attn[r][m][hh]);
        float ex[16], sum = 0.f;
        #pragma unroll
        for (int m = 0; m < 16; ++m) { ex[m] = __expf(s.v.attn[r][m][hh] - mx); sum += ex[m]; }
        const float inv = 1.f / sum;
        #pragma unroll
        for (int m = 0; m < 16; ++m) s.v.attn[r][m][hh] = ex[m] * inv;
    }
    __syncthreads();

    // ---- P4: Z[r][hh][d] = sum_m attn[r][m][hh] * h[nl[r][m]][d]
    //      1024 threads: 64 threads/node, 2 d each.  (f16, swizzled)
    {
        const int r = t >> 6, dc = t & 63, d0 = dc * 2;
        float z[8][2];
        #pragma unroll
        for (int hh = 0; hh < 8; ++hh) { z[hh][0] = 0.f; z[hh][1] = 0.f; }
        #pragma unroll 4
        for (int m = 0; m < 16; ++m) {
            const int nbr = s.nls[r][m];
            const float2 hv = P::ld2(h, (long)(b * N_ + nbr) * 128 + d0);
            const float4 a0 = *(const float4*)&s.v.attn[r][m][0];
            const float4 a1 = *(const float4*)&s.v.attn[r][m][4];
            const float av[8] = { a0.x, a0.y, a0.z, a0.w, a1.x, a1.y, a1.z, a1.w };
            #pragma unroll
            for (int hh = 0; hh < 8; ++hh) {
                z[hh][0] += av[hh] * hv.x;
                z[hh][1] += av[hh] * hv.y;
            }
        }
        char* zb = (char*)&s.u.Zh[0][0] + r * 2048;
        const int xo = (r & 7) << 4;
        #pragma unroll
        for (int hh = 0; hh < 8; ++hh) {
            f16x2 vv;
            vv[0] = (_Float16)z[hh][0];
            vv[1] = (_Float16)z[hh][1];
            *(f16x2*)(zb + ((hh * 256 + dc * 4) ^ xo)) = vv;
        }
    }
    __syncthreads();

    // ---- G1: yln = Zh @ WeffT^T + hs   (MFMA 16x16x16, K=1024 split in 2)
    //      wave w: cols wo*16..wo*16+15, K-half kh.  32 MFMAs per wave.
    {
        const char* za  = (const char*)&s.u.Zh[0][0] + lo * 2048;
        const int   xo  = (lo & 7) << 4;
        const char* wb0 = (const char*)(WeffT + (size_t)(wo * 16 + lo) * 1024) + kh * 1024;
        f32x4 acc0 = {0.f, 0.f, 0.f, 0.f};
        #pragma unroll 8
        for (int ks = 0; ks < 32; ++ks) {
            const int kb  = ks * 32 + hi * 8;          // bytes within the half
            const f16x4 a  = *(const f16x4*)(za + ((kh * 1024 + kb) ^ xo));
            const f16x4 b0 = *(const f16x4*)(wb0 + kb);
            acc0 = __builtin_amdgcn_mfma_f32_16x16x16f16(a, b0, acc0, 0, 0, 0);
        }
        const int o0 = wo * 16 + lo;
        #pragma unroll
        for (int q = 0; q < 4; ++q) {
            const int rr = hi * 4 + q;
            if (kh == 0) s.v.yln[rr][o0] = acc0[q] + s.hs[rr][o0];
            else         s.part[rr][o0]  = acc0[q];
        }
    }
    __syncthreads();
    {   // reduce partials: 2048 elems, 2 per thread
        const int i = t * 2;
        float* yp = &s.v.yln[0][0];
        const float2 pv = *(const float2*)(&s.part[0][0] + i);
        float2 yv = *(const float2*)(yp + i);
        yv.x += pv.x; yv.y += pv.y;
        *(float2*)(yp + i) = yv;
    }
    __syncthreads();

    // ---- LN1 -> ts (f32, padded rows). 16 threads per row (256 threads).
    if (t < NB * 16) {
        const int r = t >> 4, j0 = (t & 15) * 8;
        const float4 x0 = *(const float4*)&s.v.yln[r][j0];
        const float4 x1 = *(const float4*)&s.v.yln[r][j0 + 4];
        const float x[8] = { x0.x, x0.y, x0.z, x0.w, x1.x, x1.y, x1.z, x1.w };
        float sm = 0.f, ss = 0.f;
        #pragma unroll
        for (int j = 0; j < 8; ++j) { sm += x[j]; ss += x[j] * x[j]; }
        #pragma unroll
        for (int off = 8; off > 0; off >>= 1) {
            sm += __shfl_xor(sm, off);
            ss += __shfl_xor(ss, off);
        }
        const float mu   = sm * (1.f / 128.f);
        const float var  = ss * (1.f / 128.f) - mu * mu;
        const float rstd = rsqrtf(var + 1e-5f);
        float gv[8], bv[8];
        P::ld8(g1, j0, gv);
        P::ld8(bb1, j0, bv);
        #pragma unroll
        for (int j = 0; j < 8; ++j)
            s.u.ff.ts[r][j0 + j] = (x[j] - mu) * rstd * gv[j] + bv[j];
    }
    __syncthreads();

    // ---- FF1: us = relu(ts @ w1 + b1)  (MFMA; 16 waves x 16 cols; K=128)
    {
        const int o = w * 16 + lo;
        f32x4 acc = {0.f, 0.f, 0.f, 0.f};
        #pragma unroll
        for (int ks = 0; ks < 8; ++ks) {
            const int k = ks * 16 + hi * 4;
            const float4 tv = *(const float4*)&s.u.ff.ts[lo][k];
            f16x4 a;
            a[0] = (_Float16)tv.x; a[1] = (_Float16)tv.y;
            a[2] = (_Float16)tv.z; a[3] = (_Float16)tv.w;
            f16x4 bb;
            #pragma unroll
            for (int j = 0; j < 4; ++j) bb[j] = (_Float16)P::ld(w1, (k + j) * 256 + o);
            acc = __builtin_amdgcn_mfma_f32_16x16x16f16(a, bb, acc, 0, 0, 0);
        }
        const float bias = P::ld(fb1, o);
        #pragma unroll
        for (int q = 0; q < 4; ++q)
            s.u.ff.us[hi * 4 + q][o] = (_Float16)fmaxf(acc[q] + bias, 0.f);
    }
    __syncthreads();

    // ---- FF2: ys = us @ w2 + b2 + ts  (MFMA; 8 col-groups x 2 K-halves)
    {
        const int o0 = wo * 16 + lo;
        f32x4 acc = {0.f, 0.f, 0.f, 0.f};
        #pragma unroll
        for (int ks = 0; ks < 8; ++ks) {
            const int k = kh * 128 + ks * 16 + hi * 4;
            const f16x4 a = *(const f16x4*)&s.u.ff.us[lo][k];
            f16x4 bb;
            #pragma unroll
            for (int j = 0; j < 4; ++j) bb[j] = (_Float16)P::ld(w2, (k + j) * 128 + o0);
            acc = __builtin_amdgcn_mfma_f32_16x16x16f16(a, bb, acc, 0, 0, 0);
        }
        const float bias = P::ld(fb2, o0);
        #pragma unroll
        for (int q = 0; q < 4; ++q) {
            const int rr = hi * 4 + q;
            if (kh == 0) s.u.ff.ys[rr][o0] = acc[q] + bias + s.u.ff.ts[rr][o0];
            else         s.part[rr][o0]    = acc[q];
        }
    }
    __syncthreads();
    {   // reduce partials: 2048 elems, 2 per thread
        const int i = t * 2;
        float* yp = &s.u.ff.ys[0][0];
        const float2 pv = *(const float2*)(&s.part[0][0] + i);
        float2 yv = *(const float2*)(yp + i);
        yv.x += pv.x; yv.y += pv.y;
        *(float2*)(yp + i) = yv;
    }
    __syncthreads();

    // ---- LN2 -> out. 16 threads per row (256 threads).
    if (t < NB * 16) {
        const int r = t >> 4, j0 = (t & 15) * 8;
        const float4 x0 = *(const float4*)&s.u.ff.ys[r][j0];
        const float4 x1 = *(const float4*)&s.u.ff.ys[r][j0 + 4];
        const float x[8] = { x0.x, x0.y, x0.z, x0.w, x1.x, x1.y, x1.z, x1.w };
        float sm = 0.f, ss = 0.f;
        #pragma unroll
        for (int j = 0; j < 8; ++j) { sm += x[j]; ss += x[j] * x[j]; }
        #pragma unroll
        for (int off = 8; off > 0; off >>= 1) {
            sm += __shfl_xor(sm, off);
            ss += __shfl_xor(ss, off);
        }
        const float mu   = sm * (1.f / 128.f);
        const float var  = ss * (1.f / 128.f) - mu * mu;
        const float rstd = rsqrtf(var + 1e-5f);
        float gv[8], bv[8], o8[8];
        P::ld8(g2, j0, gv);
        P::ld8(bb2, j0, bv);
        #pragma unroll
        for (int j = 0; j < 8; ++j) o8[j] = (x[j] - mu) * rstd * gv[j] + bv[j];
        P::st8(out, (long)(bn0 + r) * 128 + j0, o8);
    }
}

__global__ __launch_bounds__(1024) void k_gat(
        const void* __restrict__ h,
        const int*  __restrict__ adj,
        const int*  __restrict__ n_list,
        const _Float16* __restrict__ ssrc_h,
        const _Float16* __restrict__ sdst_h,
        const _Float16* __restrict__ WeffT,
        const void* __restrict__ g1, const void* __restrict__ bb1,
        const void* __restrict__ w1, const void* __restrict__ fb1,
        const void* __restrict__ w2, const void* __restrict__ fb2,
        const void* __restrict__ g2, const void* __restrict__ bb2,
        void* __restrict__ out) {
    __shared__ Smem s;
    if (probe_is_f32(h))
        gat_body<true >(s, h, adj, n_list, ssrc_h, sdst_h, WeffT,
                        g1, bb1, w1, fb1, w2, fb2, g2, bb2, out);
    else
        gat_body<false>(s, h, adj, n_list, ssrc_h, sdst_h, WeffT,
                        g1, bb1, w1, fb1, w2, fb2, g2, bb2, out);
}

// ---------------------------------------------------------------------------
extern "C" void kernel_launch(void* const* d_in, const int* in_sizes, int n_in,
                              void* d_out, int out_size, void* d_ws, size_t ws_size,
                              hipStream_t stream) {
    (void)in_sizes; (void)n_in; (void)out_size; (void)ws_size;

    // ws layout (bytes) — total 532480, identical footprint to the proven kernel:
    //   wsrc   [     0,   4096)  f32[1024]
    //   wdst   [  4096,   8192)  f32[1024]
    //   ssrc   [  8192, 139264)  f16[8192*8]
    //   sdst   [139264, 270336)  f16[8192*8]
    //   WeffT  [270336, 532480)  f16[128][1024]
    char* wsb = (char*)d_ws;
    float*     wsrc  = (float*)(wsb);
    float*     wdst  = (float*)(wsb + 4096);
    _Float16*  ssrc  = (_Float16*)(wsb + 8192);
    _Float16*  sdst  = (_Float16*)(wsb + 139264);
    _Float16*  WeffT = (_Float16*)(wsb + 270336);

    k0<<<520,      256, 0, stream>>>(d_in[3], d_in[6], d_in[4], d_in[5], d_in[0],
                                     wsrc, wdst, WeffT);
    k1<<<BN_ / 16, 256, 0, stream>>>(d_in[0], wsrc, wdst, ssrc, sdst);
    k_gat<<<BN_ / NB, 1024, 0, stream>>>(
        d_in[0], (const int*)d_in[1], (const int*)d_in[2], ssrc, sdst, WeffT,
        d_in[7], d_in[8], d_in[9], d_in[10], d_in[11], d_in[12],
        d_in[13], d_in[14], d_out);
}